// Round 5
// baseline (155.424 us; speedup 1.0000x reference)
//
#include <hip/hip_runtime.h>

typedef unsigned long long u64;
typedef unsigned int u32;

#define KC 1024
#define TOPK 750
#define CONF 0.3f
#define IOU_T 0.01f
#define WINB 0x2F80u        // window base: scores in (0.3,1] -> key prefix 0x2FA6..0x2FE0
#define NW 128              // window bins
#define CCAP 2048

// exact f32 op order of the reference softmax + mask; key = (monotone score bits, ~index)
__device__ __forceinline__ u64 score_key(const float* __restrict__ c2, u32 p) {
    float a0 = c2[0], a1 = c2[1];
    float m  = fmaxf(a0, a1);
    float e0 = expf(a0 - m), e1 = expf(a1 - m);
    float s  = e1 / (e0 + e1);
    float ms = s > CONF ? s : -1.0f;
    u32 u = __float_as_uint(ms);
    u32 mapped = (u & 0x80000000u) ? ~u : (u | 0x80000000u);
    return ((u64)mapped << 32) | (u32)(~p);
}

// exact f32 op order of the reference decode; key==0 -> invalid placeholder
__device__ __forceinline__ void decode_key(u64 key, int b, int tid,
        const float* __restrict__ bl, const float* __restrict__ priors, int P,
        float& x1, float& y1, float& x2, float& y2, float& score, bool& valid) {
    u32 mapped = (u32)(key >> 32);
    u32 fb = (mapped & 0x80000000u) ? (mapped & 0x7fffffffu) : ~mapped;
    float s = __uint_as_float(fb);
    u32 p = ~(u32)(key & 0xffffffffull);
    if (key == 0ull) { s = -1.0f; p = (u32)tid; }   // placeholder: safe index, invalid
    score = s; valid = (s > CONF);
    const float* pr4 = priors + (size_t)p * 4;
    const float* lc  = bl + ((size_t)b * P + p) * 4;
    float pcx = pr4[0], pcy = pr4[1], pw = pr4[2], ph = pr4[3];
    float lx = lc[0], ly = lc[1], lw = lc[2], lh = lc[3];
    float cx = pcx + lx * 0.1f * pw;
    float cy = pcy + ly * 0.1f * ph;
    float w  = pw * expf(lw * 0.2f);
    float h  = ph * expf(lh * 0.2f);
    float t1x = cx - w * 0.5f;
    float t1y = cy - h * 0.5f;
    x1 = t1x * 1024.0f;
    y1 = t1y * 1024.0f;
    x2 = (t1x + w) * 1024.0f;
    y2 = (t1y + h) * 1024.0f;
}

// ---------------- K1: per-batch 128-bin window histogram ----------------
__global__ __launch_bounds__(1024) void k_hist(const float* __restrict__ cls,
                                               u32* __restrict__ hist, int P) {
    __shared__ u32 lh[NW];
    int t = threadIdx.x;
    if (t < NW) lh[t] = 0;
    __syncthreads();
    int p = blockIdx.x * 1024 + t;
    int b = blockIdx.y;
    if (p < P) {
        u64 k = score_key(cls + ((size_t)b * P + p) * 2, (u32)p);
        u32 wbin = (u32)(k >> 50) - WINB;
        if (wbin < (u32)NW) atomicAdd(&lh[wbin], 1u);   // below-window (-1.0) not counted
    }
    __syncthreads();
    if (t < NW) { u32 c = lh[t]; if (c) atomicAdd(&hist[(size_t)b * NW + t], c); }
}

// ---------------- K2: cutoff (in-block) + counting-sort scatter into bin segments ----------------
__global__ __launch_bounds__(256) void k_compact(const float* __restrict__ cls,
        const u32* __restrict__ hist, u32* __restrict__ sufx, u32* __restrict__ tot,
        u32* __restrict__ bfill, u64* __restrict__ cbuf2, int P) {
    int b = blockIdx.y, t = threadIdx.x;
    __shared__ u32 sh[NW], sa[NW], sb_[NW];
    __shared__ int sh_cut;
    if (t == 0) sh_cut = 0;
    if (t < NW) { u32 h = hist[(size_t)b * NW + t]; sh[t] = h; sa[t] = h; }
    __syncthreads();
    u32 *src = sa, *dst = sb_;
    for (int d = 1; d < NW; d <<= 1) {           // inclusive suffix sums, 7 steps
        if (t < NW) dst[t] = src[t] + ((t + d < NW) ? src[t + d] : 0u);
        __syncthreads();
        u32* tmp = src; src = dst; dst = tmp;
    }
    if (t < NW && src[t] >= KC) atomicMax(&sh_cut, t);
    __syncthreads();
    int cutw = sh_cut;                            // 0-fallback: select whole window
    if (blockIdx.x == 0) {
        if (t < NW) sufx[(size_t)b * NW + t] = src[t] - sh[t];
        if (t == 0) tot[b] = src[cutw];
    }
    int p = blockIdx.x * 256 + t;
    if (p < P) {
        u64 k = score_key(cls + ((size_t)b * P + p) * 2, (u32)p);
        u32 wbin = (u32)(k >> 50) - WINB;
        if (wbin < (u32)NW && (int)wbin >= cutw) {
            u32 pos = (src[wbin] - sh[wbin]) + atomicAdd(&bfill[(size_t)b * NW + wbin], 1u);
            if (pos < CCAP) cbuf2[(size_t)b * CCAP + pos] = k;
        }
    }
}

// ---------------- K3: exact rank within bin segment -> scatter top-1024 ----------------
__global__ void k_rank(const u64* __restrict__ cbuf2, const u32* __restrict__ hist,
                       const u32* __restrict__ sufx, const u32* __restrict__ tot,
                       u64* __restrict__ csorted) {
    int b = blockIdx.y;
    u32 s = blockIdx.x * 64 + threadIdx.x;
    u32 T = tot[b]; if (T > CCAP) T = CCAP;
    if (s >= T) return;
    const u64* cb = cbuf2 + (size_t)b * CCAP;
    u64 key = cb[s];
    u32 w = (u32)(key >> 50) - WINB;
    u32 seg0 = sufx[(size_t)b * NW + w];
    u32 segN = seg0 + hist[(size_t)b * NW + w];
    if (segN > T) segN = T;
    u32 cnt = 0;
    for (u32 j = seg0; j < segN; ++j) cnt += (cb[j] > key) ? 1u : 0u;   // keys unique
    u32 r = seg0 + cnt;                      // exact global rank (desc)
    if (r < KC) csorted[(size_t)b * KC + r] = key;
}

// ---------------- K4: decode + off + IoU suppression bitmatrix ----------------
__global__ __launch_bounds__(1024) void k_iou(const u64* __restrict__ csorted,
        const float* __restrict__ bl, const float* __restrict__ priors,
        u64* __restrict__ rows, int P) {
    int b = blockIdx.y, tid = threadIdx.x;
    int rowbase = blockIdx.x * 16;
    __shared__ float sx1[KC], sy1[KC], sx2[KC], sy2[KC], sar[KC];
    __shared__ float smax[KC];
    float x1, y1, x2, y2, score; bool valid;
    decode_key(csorted[(size_t)b * KC + tid], b, tid, bl, priors, P,
               x1, y1, x2, y2, score, valid);
    smax[tid] = valid ? fmaxf(fmaxf(x1, y1), fmaxf(x2, y2)) : 0.0f;
    __syncthreads();
    for (int st = 512; st > 0; st >>= 1) {
        if (tid < st) smax[tid] = fmaxf(smax[tid], smax[tid + st]);
        __syncthreads();
    }
    float off = smax[0] + 1.0f;
    float xs1 = x1 + off, ys1 = y1 + off, xs2 = x2 + off, ys2 = y2 + off;
    sx1[tid] = xs1; sy1[tid] = ys1; sx2[tid] = xs2; sy2[tid] = ys2;
    sar[tid] = (xs2 - xs1) * (ys2 - ys1);
    __syncthreads();

    int w = tid >> 6, lane = tid & 63;
    int r = rowbase + w;
    float rx1 = sx1[r], ry1 = sy1[r], rx2 = sx2[r], ry2 = sy2[r], rar = sar[r];
    u64* rb = rows + ((size_t)b * KC + r) * 16;
    #pragma unroll 4
    for (int c = 0; c < 16; ++c) {
        int col = c * 64 + lane;
        float ltx = fmaxf(rx1, sx1[col]), lty = fmaxf(ry1, sy1[col]);
        float rbx = fminf(rx2, sx2[col]), rby = fminf(ry2, sy2[col]);
        float ww = fmaxf(rbx - ltx, 0.0f), hh = fmaxf(rby - lty, 0.0f);
        float inter = ww * hh;
        float uni = rar + sar[col] - inter;
        float iou = inter / fmaxf(uni, 1e-9f);
        bool pred = (iou > IOU_T) && (col != r);
        u64 m = __ballot(pred);
        if (lane == 0) rb[c] = m;
    }
}

// ---------------- K5: skip-list greedy scan + decode + output ----------------
__global__ __launch_bounds__(1024) void k_scan(const u64* __restrict__ csorted,
        const u64* __restrict__ rows, const float* __restrict__ bl,
        const float* __restrict__ priors, float* __restrict__ out, int P, int B) {
    int b = blockIdx.x, tid = threadIdx.x;
    __shared__ u64 vw[16], keepw[16];
    float x1, y1, x2, y2, score; bool valid;
    decode_key(csorted[(size_t)b * KC + tid], b, tid, bl, priors, P,
               x1, y1, x2, y2, score, valid);
    u64 bal = __ballot(valid);
    if ((tid & 63) == 0) vw[tid >> 6] = bal;
    __syncthreads();

    if (tid < 16) {
        int lane = tid;
        u64 supp = ~vw[lane];                  // invalid = pre-suppressed
        u64 kw = 0;
        const u64* rb = rows + (size_t)b * KC * 16;
        for (int w = 0; w < 16; ++w) {
            u64 sw = __shfl(supp, w);
            u64 rem = ~sw;
            while (rem) {
                int bit = __ffsll((long long)rem) - 1;   // next kept box
                int i = w * 64 + bit;
                supp |= rb[(size_t)i * 16 + lane];
                if (lane == w) kw |= 1ull << bit;
                sw = __shfl(supp, w);
                u64 above = (bit == 63) ? 0ull : (~0ull << (bit + 1));
                rem = ~sw & above;
            }
        }
        keepw[lane] = kw;
    }
    __syncthreads();

    int wq = tid >> 6, bq = tid & 63;
    u64 myw = keepw[wq];
    bool kept = (myw >> bq) & 1ull;
    int rank = 0, nk = 0;
    #pragma unroll
    for (int w2 = 0; w2 < 16; ++w2) {
        int pc = __popcll(keepw[w2]);
        nk += pc;
        if (w2 < wq) rank += pc;
    }
    rank += __popcll(myw & ((1ull << bq) - 1ull));

    float* ob  = out;
    float* osc = out + (size_t)B * TOPK * 4;
    float* olb = osc + (size_t)B * TOPK;
    float* omk = olb + (size_t)B * TOPK;

    if (kept && rank < TOPK) {
        size_t o = (size_t)b * TOPK + rank;
        ob[o * 4 + 0] = x1; ob[o * 4 + 1] = y1;
        ob[o * 4 + 2] = x2; ob[o * 4 + 3] = y2;
        osc[o] = score;
        olb[o] = 1.0f;
        omk[o] = 1.0f;
    }
    int zstart = nk < TOPK ? nk : TOPK;
    if (tid >= zstart && tid < TOPK) {
        size_t o = (size_t)b * TOPK + tid;
        ob[o * 4 + 0] = 0.0f; ob[o * 4 + 1] = 0.0f;
        ob[o * 4 + 2] = 0.0f; ob[o * 4 + 3] = 0.0f;
        osc[o] = 0.0f;
        olb[o] = 0.0f;
        omk[o] = 0.0f;
    }
}

extern "C" void kernel_launch(void* const* d_in, const int* in_sizes, int n_in,
                              void* d_out, int out_size, void* d_ws, size_t ws_size,
                              hipStream_t stream) {
    const float* boxes_logits = (const float*)d_in[0];
    const float* cls_logits   = (const float*)d_in[1];
    const float* priors       = (const float*)d_in[2];
    int P = in_sizes[2] / 4;
    int B = in_sizes[0] / (P * 4);
    float* out = (float*)d_out;
    char* wsb = (char*)d_ws;

    // layout: [hist | bfill | csorted] (memset) then [sufx | tot | cbuf2 | rows]
    size_t HIST_B  = (size_t)B * NW * sizeof(u32);     //   8 KB
    size_t BFILL_B = (size_t)B * NW * sizeof(u32);     //   8 KB
    size_t CSORT_B = (size_t)B * KC * sizeof(u64);     // 128 KB
    size_t SUFX_B  = (size_t)B * NW * sizeof(u32);     //   8 KB
    size_t TOT_B   = 256;
    size_t CBUF2_B = (size_t)B * CCAP * sizeof(u64);   // 256 KB
    u32* hist    = (u32*)wsb;
    u32* bfill   = (u32*)(wsb + HIST_B);
    u64* csorted = (u64*)(wsb + HIST_B + BFILL_B);
    u32* sufx    = (u32*)(wsb + HIST_B + BFILL_B + CSORT_B);
    u32* tot     = (u32*)(wsb + HIST_B + BFILL_B + CSORT_B + SUFX_B);
    u64* cbuf2   = (u64*)(wsb + HIST_B + BFILL_B + CSORT_B + SUFX_B + TOT_B);
    u64* rows    = (u64*)(wsb + HIST_B + BFILL_B + CSORT_B + SUFX_B + TOT_B + CBUF2_B);
    // total ~2.5 MB of ws

    hipMemsetAsync(wsb, 0, HIST_B + BFILL_B + CSORT_B, stream);   // 144 KB, single fill

    hipLaunchKernelGGL(k_hist,    dim3((P + 1023) / 1024, B), dim3(1024), 0, stream,
                       cls_logits, hist, P);
    hipLaunchKernelGGL(k_compact, dim3((P + 255) / 256, B),   dim3(256),  0, stream,
                       cls_logits, hist, sufx, tot, bfill, cbuf2, P);
    hipLaunchKernelGGL(k_rank,    dim3(CCAP / 64, B),         dim3(64),   0, stream,
                       cbuf2, hist, sufx, tot, csorted);
    hipLaunchKernelGGL(k_iou,     dim3(KC / 16, B),           dim3(1024), 0, stream,
                       csorted, boxes_logits, priors, rows, P);
    hipLaunchKernelGGL(k_scan,    dim3(B),                    dim3(1024), 0, stream,
                       csorted, rows, boxes_logits, priors, out, P, B);
}

// Round 6
// 154.013 us; speedup vs baseline: 1.0092x; 1.0092x over previous
//
#include <hip/hip_runtime.h>

typedef unsigned long long u64;
typedef unsigned int u32;

#define KC 1024
#define TOPK 750
#define CONF 0.3f
#define IOU_T 0.01f
#define WINB 0x2F80u        // window base: scores in (0.3,1] -> key prefix 0x2FA6..0x2FE0
#define NW 128              // window bins
#define CCAP 2048

// exact f32 op order of the reference softmax + mask; key = (monotone score bits, ~index)
__device__ __forceinline__ u64 score_key(const float* __restrict__ c2, u32 p) {
    float a0 = c2[0], a1 = c2[1];
    float m  = fmaxf(a0, a1);
    float e0 = expf(a0 - m), e1 = expf(a1 - m);
    float s  = e1 / (e0 + e1);
    float ms = s > CONF ? s : -1.0f;
    u32 u = __float_as_uint(ms);
    u32 mapped = (u & 0x80000000u) ? ~u : (u | 0x80000000u);
    return ((u64)mapped << 32) | (u32)(~p);
}

// ---------------- K1: per-batch 128-bin window histogram ----------------
__global__ __launch_bounds__(1024) void k_hist(const float* __restrict__ cls,
                                               u32* __restrict__ hist, int P) {
    __shared__ u32 lh[NW];
    int t = threadIdx.x;
    if (t < NW) lh[t] = 0;
    __syncthreads();
    int p = blockIdx.x * 1024 + t;
    int b = blockIdx.y;
    if (p < P) {
        u64 k = score_key(cls + ((size_t)b * P + p) * 2, (u32)p);
        u32 wbin = (u32)(k >> 50) - WINB;
        if (wbin < (u32)NW) atomicAdd(&lh[wbin], 1u);   // masked -1.0 not in window
    }
    __syncthreads();
    if (t < NW) { u32 c = lh[t]; if (c) atomicAdd(&hist[(size_t)b * NW + t], c); }
}

// ---------------- K2: cutoff (in-block) + counting-sort scatter into bin segments ----------------
__global__ __launch_bounds__(256) void k_compact(const float* __restrict__ cls,
        const u32* __restrict__ hist, u32* __restrict__ sufx, u32* __restrict__ tot,
        u32* __restrict__ bfill, u64* __restrict__ cbuf2, int P) {
    int b = blockIdx.y, t = threadIdx.x;
    __shared__ u32 sh[NW], sa[NW], sb_[NW];
    __shared__ int sh_cut;
    if (t == 0) sh_cut = 0;
    if (t < NW) { u32 h = hist[(size_t)b * NW + t]; sh[t] = h; sa[t] = h; }
    __syncthreads();
    u32 *src = sa, *dst = sb_;
    for (int d = 1; d < NW; d <<= 1) {           // inclusive suffix sums, 7 steps
        if (t < NW) dst[t] = src[t] + ((t + d < NW) ? src[t + d] : 0u);
        __syncthreads();
        u32* tmp = src; src = dst; dst = tmp;
    }
    if (t < NW && src[t] >= KC) atomicMax(&sh_cut, t);
    __syncthreads();
    int cutw = sh_cut;                            // 0-fallback: select whole window
    if (blockIdx.x == 0) {
        if (t < NW) sufx[(size_t)b * NW + t] = src[t] - sh[t];
        if (t == 0) tot[b] = src[cutw];
    }
    int p = blockIdx.x * 256 + t;
    if (p < P) {
        u64 k = score_key(cls + ((size_t)b * P + p) * 2, (u32)p);
        u32 wbin = (u32)(k >> 50) - WINB;
        if (wbin < (u32)NW && (int)wbin >= cutw) {
            u32 pos = (src[wbin] - sh[wbin]) + atomicAdd(&bfill[(size_t)b * NW + wbin], 1u);
            if (pos < CCAP) cbuf2[(size_t)b * CCAP + pos] = k;
        }
    }
}

// ---------------- K3: exact rank within bin segment -> scatter key + decoded box ----------------
__global__ void k_rankdec(const u64* __restrict__ cbuf2, const u32* __restrict__ hist,
                          const u32* __restrict__ sufx, const u32* __restrict__ tot,
                          u64* __restrict__ csorted, float* __restrict__ cboxes,
                          const float* __restrict__ bl, const float* __restrict__ priors,
                          int P) {
    int b = blockIdx.y;
    u32 s = blockIdx.x * 64 + threadIdx.x;
    u32 T = tot[b]; if (T > CCAP) T = CCAP;
    if (s >= T) return;
    const u64* cb = cbuf2 + (size_t)b * CCAP;
    u64 key = cb[s];
    u32 w = (u32)(key >> 50) - WINB;
    u32 seg0 = sufx[(size_t)b * NW + w];
    u32 segN = seg0 + hist[(size_t)b * NW + w];
    if (segN > T) segN = T;
    u32 cnt = 0;
    for (u32 j = seg0; j < segN; ++j) cnt += (cb[j] > key) ? 1u : 0u;   // keys unique
    u32 r = seg0 + cnt;                      // exact global rank (desc)
    if (r >= KC) return;
    csorted[(size_t)b * KC + r] = key;

    // decode (exact f32 op order of the reference)
    u32 p = ~(u32)(key & 0xffffffffull);
    const float* pr4 = priors + (size_t)p * 4;
    const float* lc  = bl + ((size_t)b * P + p) * 4;
    float pcx = pr4[0], pcy = pr4[1], pw = pr4[2], ph = pr4[3];
    float lx = lc[0], ly = lc[1], lw = lc[2], lh = lc[3];
    float cx = pcx + lx * 0.1f * pw;
    float cy = pcy + ly * 0.1f * ph;
    float ww = pw * expf(lw * 0.2f);
    float hh = ph * expf(lh * 0.2f);
    float t1x = cx - ww * 0.5f;
    float t1y = cy - hh * 0.5f;
    float4 bx;
    bx.x = t1x * 1024.0f;
    bx.y = t1y * 1024.0f;
    bx.z = (t1x + ww) * 1024.0f;
    bx.w = (t1y + hh) * 1024.0f;
    *reinterpret_cast<float4*>(cboxes + ((size_t)b * KC + r) * 4) = bx;
}

// ---------------- K4: off + IoU suppression bitmatrix (coalesced, 64 rows/block) ----------------
__global__ __launch_bounds__(1024) void k_iou(const u64* __restrict__ csorted,
        const float* __restrict__ cboxes, u64* __restrict__ rows) {
    int b = blockIdx.y, tid = threadIdx.x;
    __shared__ float sx1[KC], sy1[KC], sx2[KC], sy2[KC], sar[KC];
    __shared__ float smax[KC];
    u64 key = csorted[(size_t)b * KC + tid];
    bool valid = (key != 0ull);              // window keys all have score > CONF
    float4 bx = reinterpret_cast<const float4*>(cboxes + (size_t)b * KC * 4)[tid];
    smax[tid] = valid ? fmaxf(fmaxf(bx.x, bx.y), fmaxf(bx.z, bx.w)) : 0.0f;
    __syncthreads();
    for (int st = 512; st > 0; st >>= 1) {
        if (tid < st) smax[tid] = fmaxf(smax[tid], smax[tid + st]);
        __syncthreads();
    }
    float off = smax[0] + 1.0f;
    float xs1 = bx.x + off, ys1 = bx.y + off, xs2 = bx.z + off, ys2 = bx.w + off;
    sx1[tid] = xs1; sy1[tid] = ys1; sx2[tid] = xs2; sy2[tid] = ys2;
    sar[tid] = (xs2 - xs1) * (ys2 - ys1);
    __syncthreads();

    int w = tid >> 6, lane = tid & 63;
    u64* rbb = rows + (size_t)b * KC * 16;
    #pragma unroll
    for (int rr = 0; rr < 4; ++rr) {
        int r = blockIdx.x * 64 + w * 4 + rr;
        float rx1 = sx1[r], ry1 = sy1[r], rx2 = sx2[r], ry2 = sy2[r], rar = sar[r];
        u64* rb = rbb + (size_t)r * 16;
        #pragma unroll 4
        for (int c = 0; c < 16; ++c) {
            int col = c * 64 + lane;
            float ltx = fmaxf(rx1, sx1[col]), lty = fmaxf(ry1, sy1[col]);
            float rbx = fminf(rx2, sx2[col]), rby = fminf(ry2, sy2[col]);
            float w2 = fmaxf(rbx - ltx, 0.0f), h2 = fmaxf(rby - lty, 0.0f);
            float inter = w2 * h2;
            float uni = rar + sar[col] - inter;
            float iou = inter / fmaxf(uni, 1e-9f);
            bool pred = (iou > IOU_T) && (col != r);
            u64 m = __ballot(pred);
            if (lane == 0) rb[c] = m;
        }
    }
}

// ---------------- K5: skip-list greedy scan + output ----------------
__global__ __launch_bounds__(1024) void k_scan(const u64* __restrict__ csorted,
        const u64* __restrict__ rows, const float* __restrict__ cboxes,
        float* __restrict__ out, int B) {
    int b = blockIdx.x, tid = threadIdx.x;
    __shared__ u64 vw[16], keepw[16];
    u64 key = csorted[(size_t)b * KC + tid];
    bool valid = (key != 0ull);
    u32 mapped = (u32)(key >> 32);
    u32 fb = (mapped & 0x80000000u) ? (mapped & 0x7fffffffu) : ~mapped;
    float score = __uint_as_float(fb);
    u64 bal = __ballot(valid);
    if ((tid & 63) == 0) vw[tid >> 6] = bal;
    __syncthreads();

    if (tid < 16) {
        int lane = tid;
        u64 supp = ~vw[lane];                  // invalid = pre-suppressed
        u64 kw = 0;
        const u64* rb = rows + (size_t)b * KC * 16;
        for (int w = 0; w < 16; ++w) {
            u64 sw = __shfl(supp, w);
            u64 rem = ~sw;
            while (rem) {
                int bit = __ffsll((long long)rem) - 1;   // next kept box
                int i = w * 64 + bit;
                supp |= rb[(size_t)i * 16 + lane];
                if (lane == w) kw |= 1ull << bit;
                sw = __shfl(supp, w);
                u64 above = (bit == 63) ? 0ull : (~0ull << (bit + 1));
                rem = ~sw & above;
            }
        }
        keepw[lane] = kw;
    }
    __syncthreads();

    int wq = tid >> 6, bq = tid & 63;
    u64 myw = keepw[wq];
    bool kept = (myw >> bq) & 1ull;
    int rank = 0, nk = 0;
    #pragma unroll
    for (int w2 = 0; w2 < 16; ++w2) {
        int pc = __popcll(keepw[w2]);
        nk += pc;
        if (w2 < wq) rank += pc;
    }
    rank += __popcll(myw & ((1ull << bq) - 1ull));

    float* ob  = out;
    float* osc = out + (size_t)B * TOPK * 4;
    float* olb = osc + (size_t)B * TOPK;
    float* omk = olb + (size_t)B * TOPK;

    if (kept && rank < TOPK) {
        size_t o = (size_t)b * TOPK + rank;
        float4 bx = reinterpret_cast<const float4*>(cboxes)[(size_t)b * KC + tid];
        *reinterpret_cast<float4*>(ob + o * 4) = bx;
        osc[o] = score;
        olb[o] = 1.0f;
        omk[o] = 1.0f;
    }
    int zstart = nk < TOPK ? nk : TOPK;
    if (tid >= zstart && tid < TOPK) {
        size_t o = (size_t)b * TOPK + tid;
        float4 z; z.x = z.y = z.z = z.w = 0.0f;
        *reinterpret_cast<float4*>(ob + o * 4) = z;
        osc[o] = 0.0f;
        olb[o] = 0.0f;
        omk[o] = 0.0f;
    }
}

extern "C" void kernel_launch(void* const* d_in, const int* in_sizes, int n_in,
                              void* d_out, int out_size, void* d_ws, size_t ws_size,
                              hipStream_t stream) {
    const float* boxes_logits = (const float*)d_in[0];
    const float* cls_logits   = (const float*)d_in[1];
    const float* priors       = (const float*)d_in[2];
    int P = in_sizes[2] / 4;
    int B = in_sizes[0] / (P * 4);
    float* out = (float*)d_out;
    char* wsb = (char*)d_ws;

    // layout: [hist | bfill | csorted] (memset 144KB) then [sufx | tot | cbuf2 | cboxes | rows]
    size_t HIST_B  = (size_t)B * NW * sizeof(u32);        //   8 KB
    size_t BFILL_B = (size_t)B * NW * sizeof(u32);        //   8 KB
    size_t CSORT_B = (size_t)B * KC * sizeof(u64);        // 128 KB
    size_t SUFX_B  = (size_t)B * NW * sizeof(u32);        //   8 KB
    size_t TOT_B   = 256;
    size_t CBUF2_B = (size_t)B * CCAP * sizeof(u64);      // 256 KB
    size_t CBOX_B  = (size_t)B * KC * 4 * sizeof(float);  // 256 KB
    u32* hist    = (u32*)wsb;
    u32* bfill   = (u32*)(wsb + HIST_B);
    u64* csorted = (u64*)(wsb + HIST_B + BFILL_B);
    u32* sufx    = (u32*)(wsb + HIST_B + BFILL_B + CSORT_B);
    u32* tot     = (u32*)(wsb + HIST_B + BFILL_B + CSORT_B + SUFX_B);
    u64* cbuf2   = (u64*)(wsb + HIST_B + BFILL_B + CSORT_B + SUFX_B + TOT_B);
    float* cboxes= (float*)(wsb + HIST_B + BFILL_B + CSORT_B + SUFX_B + TOT_B + CBUF2_B);
    u64* rows    = (u64*)(wsb + HIST_B + BFILL_B + CSORT_B + SUFX_B + TOT_B + CBUF2_B + CBOX_B);
    // total ~2.7 MB of ws

    hipMemsetAsync(wsb, 0, HIST_B + BFILL_B + CSORT_B, stream);   // 144 KB, single fill

    hipLaunchKernelGGL(k_hist,    dim3((P + 1023) / 1024, B), dim3(1024), 0, stream,
                       cls_logits, hist, P);
    hipLaunchKernelGGL(k_compact, dim3((P + 255) / 256, B),   dim3(256),  0, stream,
                       cls_logits, hist, sufx, tot, bfill, cbuf2, P);
    hipLaunchKernelGGL(k_rankdec, dim3(CCAP / 64, B),         dim3(64),   0, stream,
                       cbuf2, hist, sufx, tot, csorted, cboxes, boxes_logits, priors, P);
    hipLaunchKernelGGL(k_iou,     dim3(KC / 64, B),           dim3(1024), 0, stream,
                       csorted, cboxes, rows);
    hipLaunchKernelGGL(k_scan,    dim3(B),                    dim3(1024), 0, stream,
                       csorted, rows, cboxes, out, B);
}

// Round 7
// 145.931 us; speedup vs baseline: 1.0651x; 1.0554x over previous
//
#include <hip/hip_runtime.h>

typedef unsigned long long u64;
typedef unsigned int u32;

#define KC 1024
#define TOPK 750
#define CONF 0.3f
#define IOU_T 0.01f
#define WINB 0x2F80u        // window base: scores in (0.3,1] -> key prefix 0x2FA6..0x2FE0
#define NW 128              // window bins
#define CCAP 2048

// exact f32 op order of the reference softmax + mask; key = (monotone score bits, ~index)
__device__ __forceinline__ u64 score_key(const float* __restrict__ c2, u32 p) {
    float a0 = c2[0], a1 = c2[1];
    float m  = fmaxf(a0, a1);
    float e0 = expf(a0 - m), e1 = expf(a1 - m);
    float s  = e1 / (e0 + e1);
    float ms = s > CONF ? s : -1.0f;
    u32 u = __float_as_uint(ms);
    u32 mapped = (u & 0x80000000u) ? ~u : (u | 0x80000000u);
    return ((u64)mapped << 32) | (u32)(~p);
}

// ---------------- K1: fused per-batch select + rank + decode + off (1 block/batch) ----------------
__global__ __launch_bounds__(1024) void k_sel(const float* __restrict__ cls,
        const float* __restrict__ bl, const float* __restrict__ priors,
        u64* __restrict__ csorted, float* __restrict__ cboxes,
        float* __restrict__ coffs, int P) {
    int b = blockIdx.x, tid = threadIdx.x;
    __shared__ u32 sh[NW], sa[NW], sb_[NW], sufx[NW], bfill[NW];
    __shared__ int sh_cut;
    __shared__ u32 sh_T;
    __shared__ u64 keys2[CCAP];      // bin-segment scatter buffer
    __shared__ u64 ksorted[KC];      // exact-ranked top-1024
    __shared__ float smax[KC];

    if (tid < NW) { sh[tid] = 0; bfill[tid] = 0; }
    if (tid == 0) sh_cut = 0;
    ksorted[tid] = 0;                // placeholder key
    __syncthreads();

    // pass 1: window histogram (masked -1.0 falls outside window)
    const float* cb2 = cls + (size_t)b * P * 2;
    for (int i = tid; i < P; i += 1024) {
        u64 k = score_key(cb2 + (size_t)i * 2, (u32)i);
        u32 wbin = (u32)(k >> 50) - WINB;
        if (wbin < (u32)NW) atomicAdd(&sh[wbin], 1u);
    }
    __syncthreads();
    if (tid < NW) sa[tid] = sh[tid];
    __syncthreads();
    u32 *src = sa, *dst = sb_;
    for (int d = 1; d < NW; d <<= 1) {            // inclusive suffix sums, 7 steps
        if (tid < NW) dst[tid] = src[tid] + ((tid + d < NW) ? src[tid + d] : 0u);
        __syncthreads();
        u32* tmp = src; src = dst; dst = tmp;
    }
    if (tid < NW && src[tid] >= KC) atomicMax(&sh_cut, tid);
    __syncthreads();
    int cutw = sh_cut;                             // 0-fallback: whole window
    if (tid < NW) sufx[tid] = src[tid] - sh[tid];  // suffix-exclusive = segment start
    if (tid == 0) sh_T = src[cutw];
    __syncthreads();

    // pass 2: counting-sort scatter into bin segments
    for (int i = tid; i < P; i += 1024) {
        u64 k = score_key(cb2 + (size_t)i * 2, (u32)i);
        u32 wbin = (u32)(k >> 50) - WINB;
        if (wbin < (u32)NW && (int)wbin >= cutw) {
            u32 pos = sufx[wbin] + atomicAdd(&bfill[wbin], 1u);
            if (pos < CCAP) keys2[pos] = k;
        }
    }
    __syncthreads();

    // exact rank within bin segment (keys unique)
    u32 T = sh_T; if (T > CCAP) T = CCAP;
    for (int c = tid; c < (int)T; c += 1024) {
        u64 key = keys2[c];
        u32 w = (u32)(key >> 50) - WINB;
        u32 seg0 = sufx[w];
        u32 segN = seg0 + sh[w];
        if (segN > T) segN = T;
        u32 cnt = 0;
        for (u32 j = seg0; j < segN; ++j) cnt += (keys2[j] > key) ? 1u : 0u;
        u32 r = seg0 + cnt;                        // exact global rank (desc)
        if (r < KC) ksorted[r] = key;
    }
    __syncthreads();

    // decode (exact f32 op order of the reference) + materialize
    u64 key = ksorted[tid];
    bool valid = (key != 0ull);                    // window keys all have score > CONF
    float4 bx; bx.x = bx.y = bx.z = bx.w = 0.0f;
    if (valid) {
        u32 p = ~(u32)(key & 0xffffffffull);
        const float* pr4 = priors + (size_t)p * 4;
        const float* lc  = bl + ((size_t)b * P + p) * 4;
        float pcx = pr4[0], pcy = pr4[1], pw = pr4[2], ph = pr4[3];
        float lx = lc[0], ly = lc[1], lw = lc[2], lh = lc[3];
        float cx = pcx + lx * 0.1f * pw;
        float cy = pcy + ly * 0.1f * ph;
        float ww = pw * expf(lw * 0.2f);
        float hh = ph * expf(lh * 0.2f);
        float t1x = cx - ww * 0.5f;
        float t1y = cy - hh * 0.5f;
        bx.x = t1x * 1024.0f;
        bx.y = t1y * 1024.0f;
        bx.z = (t1x + ww) * 1024.0f;
        bx.w = (t1y + hh) * 1024.0f;
    }
    csorted[(size_t)b * KC + tid] = key;
    reinterpret_cast<float4*>(cboxes)[(size_t)b * KC + tid] = bx;
    smax[tid] = valid ? fmaxf(fmaxf(bx.x, bx.y), fmaxf(bx.z, bx.w)) : 0.0f;
    __syncthreads();
    for (int st = 512; st > 0; st >>= 1) {         // fmax is exact: order-independent
        if (tid < st) smax[tid] = fmaxf(smax[tid], smax[tid + st]);
        __syncthreads();
    }
    if (tid == 0) coffs[b] = smax[0] + 1.0f;
}

// ---------------- K2: IoU suppression bitmatrix (full-chip, 64 rows/block) ----------------
__global__ __launch_bounds__(1024) void k_iou(const float* __restrict__ cboxes,
        const float* __restrict__ coffs, u64* __restrict__ rows) {
    int b = blockIdx.y, tid = threadIdx.x;
    __shared__ float sx1[KC], sy1[KC], sx2[KC], sy2[KC], sar[KC];
    float off = coffs[b];
    float4 bx = reinterpret_cast<const float4*>(cboxes)[(size_t)b * KC + tid];
    float xs1 = bx.x + off, ys1 = bx.y + off, xs2 = bx.z + off, ys2 = bx.w + off;
    sx1[tid] = xs1; sy1[tid] = ys1; sx2[tid] = xs2; sy2[tid] = ys2;
    sar[tid] = (xs2 - xs1) * (ys2 - ys1);          // placeholder: zero width -> iou 0
    __syncthreads();

    int w = tid >> 6, lane = tid & 63;
    u64* rbb = rows + (size_t)b * KC * 16;
    #pragma unroll
    for (int rr = 0; rr < 4; ++rr) {
        int r = blockIdx.x * 64 + w * 4 + rr;
        float rx1 = sx1[r], ry1 = sy1[r], rx2 = sx2[r], ry2 = sy2[r], rar = sar[r];
        u64* rb = rbb + (size_t)r * 16;
        #pragma unroll 4
        for (int c = 0; c < 16; ++c) {
            int col = c * 64 + lane;
            float ltx = fmaxf(rx1, sx1[col]), lty = fmaxf(ry1, sy1[col]);
            float rbx = fminf(rx2, sx2[col]), rby = fminf(ry2, sy2[col]);
            float w2 = fmaxf(rbx - ltx, 0.0f), h2 = fmaxf(rby - lty, 0.0f);
            float inter = w2 * h2;
            float uni = rar + sar[col] - inter;
            float iou = inter / fmaxf(uni, 1e-9f);
            bool pred = (iou > IOU_T) && (col != r);
            u64 m = __ballot(pred);
            if (lane == 0) rb[c] = m;
        }
    }
}

// ---------------- K3: skip-list greedy scan + output ----------------
__global__ __launch_bounds__(1024) void k_scan(const u64* __restrict__ csorted,
        const u64* __restrict__ rows, const float* __restrict__ cboxes,
        float* __restrict__ out, int B) {
    int b = blockIdx.x, tid = threadIdx.x;
    __shared__ u64 vw[16], keepw[16];
    u64 key = csorted[(size_t)b * KC + tid];
    bool valid = (key != 0ull);
    u32 mapped = (u32)(key >> 32);
    u32 fb = (mapped & 0x80000000u) ? (mapped & 0x7fffffffu) : ~mapped;
    float score = __uint_as_float(fb);
    u64 bal = __ballot(valid);
    if ((tid & 63) == 0) vw[tid >> 6] = bal;
    __syncthreads();

    if (tid < 16) {
        int lane = tid;
        u64 supp = ~vw[lane];                  // invalid = pre-suppressed
        u64 kw = 0;
        const u64* rb = rows + (size_t)b * KC * 16;
        for (int w = 0; w < 16; ++w) {
            u64 sw = __shfl(supp, w);
            u64 rem = ~sw;
            while (rem) {
                int bit = __ffsll((long long)rem) - 1;   // next kept box
                int i = w * 64 + bit;
                supp |= rb[(size_t)i * 16 + lane];
                if (lane == w) kw |= 1ull << bit;
                sw = __shfl(supp, w);
                u64 above = (bit == 63) ? 0ull : (~0ull << (bit + 1));
                rem = ~sw & above;
            }
        }
        keepw[lane] = kw;
    }
    __syncthreads();

    int wq = tid >> 6, bq = tid & 63;
    u64 myw = keepw[wq];
    bool kept = (myw >> bq) & 1ull;
    int rank = 0, nk = 0;
    #pragma unroll
    for (int w2 = 0; w2 < 16; ++w2) {
        int pc = __popcll(keepw[w2]);
        nk += pc;
        if (w2 < wq) rank += pc;
    }
    rank += __popcll(myw & ((1ull << bq) - 1ull));

    float* ob  = out;
    float* osc = out + (size_t)B * TOPK * 4;
    float* olb = osc + (size_t)B * TOPK;
    float* omk = olb + (size_t)B * TOPK;

    if (kept && rank < TOPK) {
        size_t o = (size_t)b * TOPK + rank;
        float4 bx = reinterpret_cast<const float4*>(cboxes)[(size_t)b * KC + tid];
        *reinterpret_cast<float4*>(ob + o * 4) = bx;
        osc[o] = score;
        olb[o] = 1.0f;
        omk[o] = 1.0f;
    }
    int zstart = nk < TOPK ? nk : TOPK;
    if (tid >= zstart && tid < TOPK) {
        size_t o = (size_t)b * TOPK + tid;
        float4 z; z.x = z.y = z.z = z.w = 0.0f;
        *reinterpret_cast<float4*>(ob + o * 4) = z;
        osc[o] = 0.0f;
        olb[o] = 0.0f;
        omk[o] = 0.0f;
    }
}

extern "C" void kernel_launch(void* const* d_in, const int* in_sizes, int n_in,
                              void* d_out, int out_size, void* d_ws, size_t ws_size,
                              hipStream_t stream) {
    const float* boxes_logits = (const float*)d_in[0];
    const float* cls_logits   = (const float*)d_in[1];
    const float* priors       = (const float*)d_in[2];
    int P = in_sizes[2] / 4;
    int B = in_sizes[0] / (P * 4);
    float* out = (float*)d_out;
    char* wsb = (char*)d_ws;

    // ws layout: [csorted 128K | cboxes 256K | coffs 256B | rows 2M] — no memset needed
    size_t CSORT_B = (size_t)B * KC * sizeof(u64);        // 128 KB
    size_t CBOX_B  = (size_t)B * KC * 4 * sizeof(float);  // 256 KB
    size_t COFF_B  = 256;
    u64*   csorted = (u64*)wsb;
    float* cboxes  = (float*)(wsb + CSORT_B);
    float* coffs   = (float*)(wsb + CSORT_B + CBOX_B);
    u64*   rows    = (u64*)(wsb + CSORT_B + CBOX_B + COFF_B);

    hipLaunchKernelGGL(k_sel,  dim3(B),         dim3(1024), 0, stream,
                       cls_logits, boxes_logits, priors, csorted, cboxes, coffs, P);
    hipLaunchKernelGGL(k_iou,  dim3(KC / 64, B), dim3(1024), 0, stream,
                       cboxes, coffs, rows);
    hipLaunchKernelGGL(k_scan, dim3(B),         dim3(1024), 0, stream,
                       csorted, rows, cboxes, out, B);
}

// Round 8
// 138.394 us; speedup vs baseline: 1.1231x; 1.0545x over previous
//
#include <hip/hip_runtime.h>

typedef unsigned long long u64;
typedef unsigned int u32;

#define KC 1024
#define TOPK 750
#define CONF 0.3f
#define IOU_T 0.01f
#define WINB 0x2F80u        // window base: scores in (0.3,1] -> key prefix 0x2FA6..0x2FE0
#define NW 128              // window bins
#define CCAP 2048

// exact f32 op order of the reference softmax + mask; key = (monotone score bits, ~index)
__device__ __forceinline__ u64 score_key(const float* __restrict__ c2, u32 p) {
    float a0 = c2[0], a1 = c2[1];
    float m  = fmaxf(a0, a1);
    float e0 = expf(a0 - m), e1 = expf(a1 - m);
    float s  = e1 / (e0 + e1);
    float ms = s > CONF ? s : -1.0f;
    u32 u = __float_as_uint(ms);
    u32 mapped = (u & 0x80000000u) ? ~u : (u | 0x80000000u);
    return ((u64)mapped << 32) | (u32)(~p);
}

// ---------------- K1: full-chip key materialization + per-block hist segments ----------------
__global__ __launch_bounds__(256) void k_gather(const float* __restrict__ cls,
        u64* __restrict__ keys, u32* __restrict__ histseg, int P, int NBLK) {
    __shared__ u32 lh[NW];
    int t = threadIdx.x, blk = blockIdx.x, b = blockIdx.y;
    if (t < NW) lh[t] = 0;
    __syncthreads();
    int p = blk * 256 + t;
    if (p < P) {
        u64 k = score_key(cls + ((size_t)b * P + p) * 2, (u32)p);
        keys[(size_t)b * P + p] = k;
        u32 wbin = (u32)(k >> 50) - WINB;
        if (wbin < (u32)NW) atomicAdd(&lh[wbin], 1u);   // masked -1.0 outside window
    }
    __syncthreads();
    if (t < NW) histseg[((size_t)b * NBLK + blk) * NW + t] = lh[t];   // non-atomic
}

// ---------------- K2: per-batch cutoff + compact + rank + decode + off ----------------
__global__ __launch_bounds__(1024) void k_sel2(const u64* __restrict__ keys,
        const float* __restrict__ bl, const float* __restrict__ priors,
        const u32* __restrict__ histseg, u64* __restrict__ csorted,
        float* __restrict__ cboxes, float* __restrict__ coffs, int P, int NBLK) {
    int b = blockIdx.x, tid = threadIdx.x;
    __shared__ u32 sh[NW], sa[NW], sb_[NW], sufx[NW], bfill[NW];
    __shared__ u32 partial[8 * NW];
    __shared__ int sh_cut;
    __shared__ u32 sh_T;
    __shared__ u64 keys2[CCAP];      // bin-segment scatter buffer
    __shared__ u64 ksorted[KC];      // exact-ranked top-1024
    __shared__ float smax[KC];

    // sum per-block hist segments: 8 chunks x 128 bins
    {
        int bin = tid & 127, c = tid >> 7;
        u32 s = 0;
        for (int j = c; j < NBLK; j += 8)
            s += histseg[((size_t)b * NBLK + j) * NW + bin];
        partial[c * NW + bin] = s;
    }
    if (tid < NW) bfill[tid] = 0;
    if (tid == 0) sh_cut = 0;
    ksorted[tid] = 0;                // placeholder key
    __syncthreads();
    if (tid < NW) {
        u32 tot = 0;
        #pragma unroll
        for (int c = 0; c < 8; ++c) tot += partial[c * NW + tid];
        sh[tid] = tot; sa[tid] = tot;
    }
    __syncthreads();
    u32 *src = sa, *dst = sb_;
    for (int d = 1; d < NW; d <<= 1) {            // inclusive suffix sums, 7 steps
        if (tid < NW) dst[tid] = src[tid] + ((tid + d < NW) ? src[tid + d] : 0u);
        __syncthreads();
        u32* tmp = src; src = dst; dst = tmp;
    }
    if (tid < NW && src[tid] >= KC) atomicMax(&sh_cut, tid);
    __syncthreads();
    int cutw = sh_cut;                             // 0-fallback: whole window
    if (tid < NW) sufx[tid] = src[tid] - sh[tid];  // suffix-exclusive = segment start
    if (tid == 0) sh_T = src[cutw];
    __syncthreads();

    // compact keys >= cutoff bin into LDS bin segments (keys precomputed, no expf)
    const u64* kb = keys + (size_t)b * P;
    for (int i = tid; i < P; i += 1024) {
        u64 k = kb[i];
        u32 wbin = (u32)(k >> 50) - WINB;
        if (wbin < (u32)NW && (int)wbin >= cutw) {
            u32 pos = sufx[wbin] + atomicAdd(&bfill[wbin], 1u);
            if (pos < CCAP) keys2[pos] = k;
        }
    }
    __syncthreads();

    // exact rank within bin segment (keys unique)
    u32 T = sh_T; if (T > CCAP) T = CCAP;
    for (int c = tid; c < (int)T; c += 1024) {
        u64 key = keys2[c];
        u32 w = (u32)(key >> 50) - WINB;
        u32 seg0 = sufx[w];
        u32 segN = seg0 + sh[w];
        if (segN > T) segN = T;
        u32 cnt = 0;
        for (u32 j = seg0; j < segN; ++j) cnt += (keys2[j] > key) ? 1u : 0u;
        u32 r = seg0 + cnt;                        // exact global rank (desc)
        if (r < KC) ksorted[r] = key;
    }
    __syncthreads();

    // decode (exact f32 op order of the reference) + materialize
    u64 key = ksorted[tid];
    bool valid = (key != 0ull);                    // window keys all have score > CONF
    float4 bx; bx.x = bx.y = bx.z = bx.w = 0.0f;
    if (valid) {
        u32 p = ~(u32)(key & 0xffffffffull);
        const float* pr4 = priors + (size_t)p * 4;
        const float* lc  = bl + ((size_t)b * P + p) * 4;
        float pcx = pr4[0], pcy = pr4[1], pw = pr4[2], ph = pr4[3];
        float lx = lc[0], ly = lc[1], lw = lc[2], lh = lc[3];
        float cx = pcx + lx * 0.1f * pw;
        float cy = pcy + ly * 0.1f * ph;
        float ww = pw * expf(lw * 0.2f);
        float hh = ph * expf(lh * 0.2f);
        float t1x = cx - ww * 0.5f;
        float t1y = cy - hh * 0.5f;
        bx.x = t1x * 1024.0f;
        bx.y = t1y * 1024.0f;
        bx.z = (t1x + ww) * 1024.0f;
        bx.w = (t1y + hh) * 1024.0f;
    }
    csorted[(size_t)b * KC + tid] = key;
    reinterpret_cast<float4*>(cboxes)[(size_t)b * KC + tid] = bx;
    smax[tid] = valid ? fmaxf(fmaxf(bx.x, bx.y), fmaxf(bx.z, bx.w)) : 0.0f;
    __syncthreads();
    for (int st = 512; st > 0; st >>= 1) {         // fmax is exact: order-independent
        if (tid < st) smax[tid] = fmaxf(smax[tid], smax[tid + st]);
        __syncthreads();
    }
    if (tid == 0) coffs[b] = smax[0] + 1.0f;
}

// ---------------- K3: IoU suppression bitmatrix (full-chip, 64 rows/block) ----------------
__global__ __launch_bounds__(1024) void k_iou(const float* __restrict__ cboxes,
        const float* __restrict__ coffs, u64* __restrict__ rows) {
    int b = blockIdx.y, tid = threadIdx.x;
    __shared__ float sx1[KC], sy1[KC], sx2[KC], sy2[KC], sar[KC];
    float off = coffs[b];
    float4 bx = reinterpret_cast<const float4*>(cboxes)[(size_t)b * KC + tid];
    float xs1 = bx.x + off, ys1 = bx.y + off, xs2 = bx.z + off, ys2 = bx.w + off;
    sx1[tid] = xs1; sy1[tid] = ys1; sx2[tid] = xs2; sy2[tid] = ys2;
    sar[tid] = (xs2 - xs1) * (ys2 - ys1);          // placeholder: zero width -> iou 0
    __syncthreads();

    int w = tid >> 6, lane = tid & 63;
    u64* rbb = rows + (size_t)b * KC * 16;
    #pragma unroll
    for (int rr = 0; rr < 4; ++rr) {
        int r = blockIdx.x * 64 + w * 4 + rr;
        float rx1 = sx1[r], ry1 = sy1[r], rx2 = sx2[r], ry2 = sy2[r], rar = sar[r];
        u64* rb = rbb + (size_t)r * 16;
        #pragma unroll 4
        for (int c = 0; c < 16; ++c) {
            int col = c * 64 + lane;
            float ltx = fmaxf(rx1, sx1[col]), lty = fmaxf(ry1, sy1[col]);
            float rbx = fminf(rx2, sx2[col]), rby = fminf(ry2, sy2[col]);
            float w2 = fmaxf(rbx - ltx, 0.0f), h2 = fmaxf(rby - lty, 0.0f);
            float inter = w2 * h2;
            float uni = rar + sar[col] - inter;
            float iou = inter / fmaxf(uni, 1e-9f);
            bool pred = (iou > IOU_T) && (col != r);
            u64 m = __ballot(pred);
            if (lane == 0) rb[c] = m;
        }
    }
}

// ---------------- K4: skip-list greedy scan + output ----------------
__global__ __launch_bounds__(1024) void k_scan(const u64* __restrict__ csorted,
        const u64* __restrict__ rows, const float* __restrict__ cboxes,
        float* __restrict__ out, int B) {
    int b = blockIdx.x, tid = threadIdx.x;
    __shared__ u64 vw[16], keepw[16];
    u64 key = csorted[(size_t)b * KC + tid];
    bool valid = (key != 0ull);
    u32 mapped = (u32)(key >> 32);
    u32 fb = (mapped & 0x80000000u) ? (mapped & 0x7fffffffu) : ~mapped;
    float score = __uint_as_float(fb);
    u64 bal = __ballot(valid);
    if ((tid & 63) == 0) vw[tid >> 6] = bal;
    __syncthreads();

    if (tid < 16) {
        int lane = tid;
        u64 supp = ~vw[lane];                  // invalid = pre-suppressed
        u64 kw = 0;
        const u64* rb = rows + (size_t)b * KC * 16;
        for (int w = 0; w < 16; ++w) {
            u64 sw = __shfl(supp, w);
            u64 rem = ~sw;
            while (rem) {
                int bit = __ffsll((long long)rem) - 1;   // next kept box
                int i = w * 64 + bit;
                supp |= rb[(size_t)i * 16 + lane];
                if (lane == w) kw |= 1ull << bit;
                sw = __shfl(supp, w);
                u64 above = (bit == 63) ? 0ull : (~0ull << (bit + 1));
                rem = ~sw & above;
            }
        }
        keepw[lane] = kw;
    }
    __syncthreads();

    int wq = tid >> 6, bq = tid & 63;
    u64 myw = keepw[wq];
    bool kept = (myw >> bq) & 1ull;
    int rank = 0, nk = 0;
    #pragma unroll
    for (int w2 = 0; w2 < 16; ++w2) {
        int pc = __popcll(keepw[w2]);
        nk += pc;
        if (w2 < wq) rank += pc;
    }
    rank += __popcll(myw & ((1ull << bq) - 1ull));

    float* ob  = out;
    float* osc = out + (size_t)B * TOPK * 4;
    float* olb = osc + (size_t)B * TOPK;
    float* omk = olb + (size_t)B * TOPK;

    if (kept && rank < TOPK) {
        size_t o = (size_t)b * TOPK + rank;
        float4 bx = reinterpret_cast<const float4*>(cboxes)[(size_t)b * KC + tid];
        *reinterpret_cast<float4*>(ob + o * 4) = bx;
        osc[o] = score;
        olb[o] = 1.0f;
        omk[o] = 1.0f;
    }
    int zstart = nk < TOPK ? nk : TOPK;
    if (tid >= zstart && tid < TOPK) {
        size_t o = (size_t)b * TOPK + tid;
        float4 z; z.x = z.y = z.z = z.w = 0.0f;
        *reinterpret_cast<float4*>(ob + o * 4) = z;
        osc[o] = 0.0f;
        olb[o] = 0.0f;
        omk[o] = 0.0f;
    }
}

extern "C" void kernel_launch(void* const* d_in, const int* in_sizes, int n_in,
                              void* d_out, int out_size, void* d_ws, size_t ws_size,
                              hipStream_t stream) {
    const float* boxes_logits = (const float*)d_in[0];
    const float* cls_logits   = (const float*)d_in[1];
    const float* priors       = (const float*)d_in[2];
    int P = in_sizes[2] / 4;
    int B = in_sizes[0] / (P * 4);
    int NBLK = (P + 255) / 256;
    float* out = (float*)d_out;
    char* wsb = (char*)d_ws;

    // ws layout: [keys 2.8M | histseg 704K | csorted 128K | cboxes 256K | coffs 256B | rows 2M]
    size_t KEYS_B  = (size_t)B * P * sizeof(u64);
    size_t HSEG_B  = (size_t)B * NBLK * NW * sizeof(u32);
    size_t CSORT_B = (size_t)B * KC * sizeof(u64);
    size_t CBOX_B  = (size_t)B * KC * 4 * sizeof(float);
    size_t COFF_B  = 256;
    u64*   keys    = (u64*)wsb;
    u32*   histseg = (u32*)(wsb + KEYS_B);
    u64*   csorted = (u64*)(wsb + KEYS_B + HSEG_B);
    float* cboxes  = (float*)(wsb + KEYS_B + HSEG_B + CSORT_B);
    float* coffs   = (float*)(wsb + KEYS_B + HSEG_B + CSORT_B + CBOX_B);
    u64*   rows    = (u64*)(wsb + KEYS_B + HSEG_B + CSORT_B + CBOX_B + COFF_B);

    hipLaunchKernelGGL(k_gather, dim3(NBLK, B),    dim3(256),  0, stream,
                       cls_logits, keys, histseg, P, NBLK);
    hipLaunchKernelGGL(k_sel2,   dim3(B),          dim3(1024), 0, stream,
                       keys, boxes_logits, priors, histseg, csorted, cboxes, coffs, P, NBLK);
    hipLaunchKernelGGL(k_iou,    dim3(KC / 64, B), dim3(1024), 0, stream,
                       cboxes, coffs, rows);
    hipLaunchKernelGGL(k_scan,   dim3(B),          dim3(1024), 0, stream,
                       csorted, rows, cboxes, out, B);
}

// Round 9
// 136.032 us; speedup vs baseline: 1.1426x; 1.0174x over previous
//
#include <hip/hip_runtime.h>

typedef unsigned long long u64;
typedef unsigned int u32;

#define KC 1024
#define TOPK 750
#define CONF 0.3f
#define IOU_T 0.01f
#define WINB 0x2F80u        // window base: scores in (0.3,1] -> key prefix 0x2FA6..0x2FE0
#define NW 128              // window bins
#define CCAP 2048

// exact f32 op order of the reference softmax + mask; key = (monotone score bits, ~index)
__device__ __forceinline__ u64 score_key(const float* __restrict__ c2, u32 p) {
    float a0 = c2[0], a1 = c2[1];
    float m  = fmaxf(a0, a1);
    float e0 = expf(a0 - m), e1 = expf(a1 - m);
    float s  = e1 / (e0 + e1);
    float ms = s > CONF ? s : -1.0f;
    u32 u = __float_as_uint(ms);
    u32 mapped = (u & 0x80000000u) ? ~u : (u | 0x80000000u);
    return ((u64)mapped << 32) | (u32)(~p);
}

// ---------------- K1: full-chip key materialization + per-block hist segments ----------------
__global__ __launch_bounds__(256) void k_gather(const float* __restrict__ cls,
        u64* __restrict__ keys, u32* __restrict__ histseg, int P, int NBLK) {
    __shared__ u32 lh[NW];
    int t = threadIdx.x, blk = blockIdx.x, b = blockIdx.y;
    if (t < NW) lh[t] = 0;
    __syncthreads();
    int p = blk * 256 + t;
    if (p < P) {
        u64 k = score_key(cls + ((size_t)b * P + p) * 2, (u32)p);
        keys[(size_t)b * P + p] = k;
        u32 wbin = (u32)(k >> 50) - WINB;
        if (wbin < (u32)NW) atomicAdd(&lh[wbin], 1u);   // masked -1.0 outside window
    }
    __syncthreads();
    if (t < NW) histseg[((size_t)b * NBLK + blk) * NW + t] = lh[t];   // non-atomic
}

// ---------------- K2: per-batch hist sum + suffix scan + cutoff; zero bfill ----------------
__global__ __launch_bounds__(1024) void k_cut(const u32* __restrict__ histseg,
        u32* __restrict__ hist_g, u32* __restrict__ sufx_g, u32* __restrict__ cutw_g,
        u32* __restrict__ tot_g, u32* __restrict__ bfill, int NBLK) {
    int b = blockIdx.x, tid = threadIdx.x;
    __shared__ u32 partial[8 * NW];
    __shared__ u32 sh[NW], sa[NW], sb_[NW];
    __shared__ int sh_cut;
    {
        int bin = tid & 127, c = tid >> 7;
        u32 s = 0;
        for (int j = c; j < NBLK; j += 8)
            s += histseg[((size_t)b * NBLK + j) * NW + bin];
        partial[c * NW + bin] = s;
    }
    if (tid == 0) sh_cut = 0;
    __syncthreads();
    if (tid < NW) {
        u32 tot = 0;
        #pragma unroll
        for (int c = 0; c < 8; ++c) tot += partial[c * NW + tid];
        sh[tid] = tot; sa[tid] = tot;
    }
    __syncthreads();
    u32 *src = sa, *dst = sb_;
    for (int d = 1; d < NW; d <<= 1) {            // inclusive suffix sums, 7 steps
        if (tid < NW) dst[tid] = src[tid] + ((tid + d < NW) ? src[tid + d] : 0u);
        __syncthreads();
        u32* tmp = src; src = dst; dst = tmp;
    }
    if (tid < NW && src[tid] >= KC) atomicMax(&sh_cut, tid);
    __syncthreads();
    int cutw = sh_cut;                             // 0-fallback: whole window
    if (tid < NW) {
        hist_g[(size_t)b * NW + tid] = sh[tid];
        sufx_g[(size_t)b * NW + tid] = src[tid] - sh[tid];  // segment start
        bfill [(size_t)b * NW + tid] = 0;
    }
    if (tid == 0) { cutw_g[b] = (u32)cutw; tot_g[b] = src[cutw]; }
}

// ---------------- K3: full-chip compact into global bin segments ----------------
__global__ __launch_bounds__(256) void k_compact2(const u64* __restrict__ keys,
        const u32* __restrict__ sufx_g, const u32* __restrict__ cutw_g,
        u32* __restrict__ bfill, u64* __restrict__ cbuf2, int P) {
    int p = blockIdx.x * 256 + threadIdx.x;
    int b = blockIdx.y;
    if (p >= P) return;
    u64 k = keys[(size_t)b * P + p];
    u32 wbin = (u32)(k >> 50) - WINB;
    if (wbin < (u32)NW && wbin >= cutw_g[b]) {
        u32 pos = sufx_g[(size_t)b * NW + wbin] + atomicAdd(&bfill[(size_t)b * NW + wbin], 1u);
        if (pos < CCAP) cbuf2[(size_t)b * CCAP + pos] = k;
    }
}

// ---------------- K4: per-batch rank + decode + off + in-LDS greedy NMS + output ----------------
__global__ __launch_bounds__(1024) void k_final(const u64* __restrict__ cbuf2,
        const u32* __restrict__ hist_g, const u32* __restrict__ sufx_g,
        const u32* __restrict__ tot_g, const float* __restrict__ bl,
        const float* __restrict__ priors, float* __restrict__ out, int P, int B) {
    int b = blockIdx.x, tid = threadIdx.x;
    __shared__ u32 sh_l[NW], sufx_l[NW];
    __shared__ u64 keys2[CCAP];
    __shared__ u64 ksorted[KC];
    __shared__ float smax[KC];
    __shared__ float sx1[KC], sy1[KC], sx2[KC], sy2[KC], sar[KC];
    __shared__ u64 vw[16], supp_s[16], keepw[16];
    __shared__ int s_cur;

    if (tid < NW) {
        sh_l[tid]   = hist_g[(size_t)b * NW + tid];
        sufx_l[tid] = sufx_g[(size_t)b * NW + tid];
    }
    ksorted[tid] = 0;                               // placeholder key
    u32 T = tot_g[b]; if (T > CCAP) T = CCAP;
    for (int i = tid; i < (int)T; i += 1024) keys2[i] = cbuf2[(size_t)b * CCAP + i];
    __syncthreads();

    // exact rank within bin segment (keys unique)
    for (int c = tid; c < (int)T; c += 1024) {
        u64 key = keys2[c];
        u32 w = (u32)(key >> 50) - WINB;
        u32 seg0 = sufx_l[w];
        u32 segN = seg0 + sh_l[w];
        if (segN > T) segN = T;
        u32 cnt = 0;
        for (u32 j = seg0; j < segN; ++j) cnt += (keys2[j] > key) ? 1u : 0u;
        u32 r = seg0 + cnt;                         // exact global rank (desc)
        if (r < KC) ksorted[r] = key;
    }
    __syncthreads();

    // decode (exact f32 op order of the reference)
    u64 key = ksorted[tid];
    bool valid = (key != 0ull);                     // window keys all have score > CONF
    u32 mapped = (u32)(key >> 32);
    u32 fbits = (mapped & 0x80000000u) ? (mapped & 0x7fffffffu) : ~mapped;
    float score = __uint_as_float(fbits);
    float4 bx; bx.x = bx.y = bx.z = bx.w = 0.0f;
    if (valid) {
        u32 p = ~(u32)(key & 0xffffffffull);
        const float* pr4 = priors + (size_t)p * 4;
        const float* lc  = bl + ((size_t)b * P + p) * 4;
        float pcx = pr4[0], pcy = pr4[1], pw = pr4[2], ph = pr4[3];
        float lx = lc[0], ly = lc[1], lw = lc[2], lh = lc[3];
        float cx = pcx + lx * 0.1f * pw;
        float cy = pcy + ly * 0.1f * ph;
        float ww = pw * expf(lw * 0.2f);
        float hh = ph * expf(lh * 0.2f);
        float t1x = cx - ww * 0.5f;
        float t1y = cy - hh * 0.5f;
        bx.x = t1x * 1024.0f;
        bx.y = t1y * 1024.0f;
        bx.z = (t1x + ww) * 1024.0f;
        bx.w = (t1y + hh) * 1024.0f;
    }
    u64 bal = __ballot(valid);
    if ((tid & 63) == 0) vw[tid >> 6] = bal;
    smax[tid] = valid ? fmaxf(fmaxf(bx.x, bx.y), fmaxf(bx.z, bx.w)) : 0.0f;
    __syncthreads();
    for (int st = 512; st > 0; st >>= 1) {          // fmax exact: order-independent
        if (tid < st) smax[tid] = fmaxf(smax[tid], smax[tid + st]);
        __syncthreads();
    }
    float off = smax[0] + 1.0f;

    // stage shifted boxes
    float xs1 = bx.x + off, ys1 = bx.y + off, xs2 = bx.z + off, ys2 = bx.w + off;
    sx1[tid] = xs1; sy1[tid] = ys1; sx2[tid] = xs2; sy2[tid] = ys2;
    sar[tid] = (xs2 - xs1) * (ys2 - ys1);           // placeholder: zero area -> iou 0
    if (tid < 16) { supp_s[tid] = ~vw[tid]; keepw[tid] = 0; }
    __syncthreads();
    if (tid == 0) {
        int nxt = -1;
        for (int w = 0; w < 16; ++w) {
            u64 rem = ~supp_s[w];
            if (rem) { nxt = w * 64 + __ffsll((long long)rem) - 1; break; }
        }
        s_cur = nxt;
    }
    __syncthreads();

    // greedy NMS: per kept box, all threads compute IoU(cur, tid) from LDS
    while (s_cur >= 0) {
        int cur = s_cur;
        float rx1 = sx1[cur], ry1 = sy1[cur], rx2 = sx2[cur], ry2 = sy2[cur], rar = sar[cur];
        float ltx = fmaxf(rx1, sx1[tid]), lty = fmaxf(ry1, sy1[tid]);
        float rbx = fminf(rx2, sx2[tid]), rby = fminf(ry2, sy2[tid]);
        float w2 = fmaxf(rbx - ltx, 0.0f), h2 = fmaxf(rby - lty, 0.0f);
        float inter = w2 * h2;
        float uni = rar + sar[tid] - inter;
        float iou = inter / fmaxf(uni, 1e-9f);
        bool pred = (iou > IOU_T) && (tid != cur);
        u64 m = __ballot(pred);
        if ((tid & 63) == 0) supp_s[tid >> 6] |= m;
        __syncthreads();
        if (tid == 0) {
            keepw[cur >> 6] |= 1ull << (cur & 63);
            supp_s[cur >> 6] |= 1ull << (cur & 63);   // mark processed
            int nxt = -1;
            int w0 = cur >> 6, bit = cur & 63;
            u64 above = (bit == 63) ? 0ull : (~0ull << (bit + 1));
            u64 rem = ~supp_s[w0] & above;
            if (rem) nxt = w0 * 64 + __ffsll((long long)rem) - 1;
            else for (int w = w0 + 1; w < 16; ++w) {
                u64 r2 = ~supp_s[w];
                if (r2) { nxt = w * 64 + __ffsll((long long)r2) - 1; break; }
            }
            s_cur = nxt;
        }
        __syncthreads();
    }

    // rank among kept (score order) + output
    int wq = tid >> 6, bq = tid & 63;
    u64 myw = keepw[wq];
    bool kept = (myw >> bq) & 1ull;
    int rank = 0, nk = 0;
    #pragma unroll
    for (int w2i = 0; w2i < 16; ++w2i) {
        int pc = __popcll(keepw[w2i]);
        nk += pc;
        if (w2i < wq) rank += pc;
    }
    rank += __popcll(myw & ((1ull << bq) - 1ull));

    float* ob  = out;
    float* osc = out + (size_t)B * TOPK * 4;
    float* olb = osc + (size_t)B * TOPK;
    float* omk = olb + (size_t)B * TOPK;

    if (kept && rank < TOPK) {
        size_t o = (size_t)b * TOPK + rank;
        *reinterpret_cast<float4*>(ob + o * 4) = bx;
        osc[o] = score;
        olb[o] = 1.0f;
        omk[o] = 1.0f;
    }
    int zstart = nk < TOPK ? nk : TOPK;
    if (tid >= zstart && tid < TOPK) {
        size_t o = (size_t)b * TOPK + tid;
        float4 z; z.x = z.y = z.z = z.w = 0.0f;
        *reinterpret_cast<float4*>(ob + o * 4) = z;
        osc[o] = 0.0f;
        olb[o] = 0.0f;
        omk[o] = 0.0f;
    }
}

extern "C" void kernel_launch(void* const* d_in, const int* in_sizes, int n_in,
                              void* d_out, int out_size, void* d_ws, size_t ws_size,
                              hipStream_t stream) {
    const float* boxes_logits = (const float*)d_in[0];
    const float* cls_logits   = (const float*)d_in[1];
    const float* priors       = (const float*)d_in[2];
    int P = in_sizes[2] / 4;
    int B = in_sizes[0] / (P * 4);
    int NBLK = (P + 255) / 256;
    float* out = (float*)d_out;
    char* wsb = (char*)d_ws;

    // ws: [keys 2.8M | histseg 704K | hist 8K | sufx 8K | cutw 256B | tot 256B | bfill 8K | cbuf2 256K]
    size_t KEYS_B = (size_t)B * P * sizeof(u64);
    size_t HSEG_B = (size_t)B * NBLK * NW * sizeof(u32);
    size_t HG_B   = (size_t)B * NW * sizeof(u32);
    u64* keys    = (u64*)wsb;
    u32* histseg = (u32*)(wsb + KEYS_B);
    u32* hist_g  = (u32*)(wsb + KEYS_B + HSEG_B);
    u32* sufx_g  = (u32*)(wsb + KEYS_B + HSEG_B + HG_B);
    u32* cutw_g  = (u32*)(wsb + KEYS_B + HSEG_B + 2 * HG_B);
    u32* tot_g   = (u32*)(wsb + KEYS_B + HSEG_B + 2 * HG_B + 256);
    u32* bfill   = (u32*)(wsb + KEYS_B + HSEG_B + 2 * HG_B + 512);
    u64* cbuf2   = (u64*)(wsb + KEYS_B + HSEG_B + 3 * HG_B + 512);

    hipLaunchKernelGGL(k_gather,   dim3(NBLK, B), dim3(256),  0, stream,
                       cls_logits, keys, histseg, P, NBLK);
    hipLaunchKernelGGL(k_cut,      dim3(B),       dim3(1024), 0, stream,
                       histseg, hist_g, sufx_g, cutw_g, tot_g, bfill, NBLK);
    hipLaunchKernelGGL(k_compact2, dim3(NBLK, B), dim3(256),  0, stream,
                       keys, sufx_g, cutw_g, bfill, cbuf2, P);
    hipLaunchKernelGGL(k_final,    dim3(B),       dim3(1024), 0, stream,
                       cbuf2, hist_g, sufx_g, tot_g, boxes_logits, priors, out, P, B);
}